// Round 1
// baseline (43.899 us; speedup 1.0000x reference)
//
#include <hip/hip_runtime.h>

// Nadaraya-Watson kernel regression:
//   scores[n,k] = -0.5 * ((q[n] - keys[n,k]) * w)^2
//   out[n]      = sum_k softmax(scores[n,:])[k] * values[n,k]
// N = 8192 rows, K = 4096 cols, all float32. Memory-bound: 256 MiB read.

#define N_ROWS 8192
#define K_DIM  4096
#define BLOCK  256
#define CHUNKS (K_DIM / (BLOCK * 4))   // 4 float4 chunks per thread

__global__ __launch_bounds__(BLOCK) void nw_regression_kernel(
    const float* __restrict__ queries,
    const float* __restrict__ keys,
    const float* __restrict__ values,
    const float* __restrict__ w,
    float* __restrict__ out)
{
    const int row  = blockIdx.x;
    const int tid  = threadIdx.x;
    const int wave = tid >> 6;
    const int lane = tid & 63;

    const float qv = queries[row];
    const float wv = w[0];

    const float4* krow = reinterpret_cast<const float4*>(keys   + (size_t)row * K_DIM);
    const float4* vrow = reinterpret_cast<const float4*>(values + (size_t)row * K_DIM);

    // Pass 1: load keys (coalesced float4, stride BLOCK), compute scores into
    // registers, track local max. Scores are all <= 0.
    float sc[CHUNKS][4];
    float lmax = -3.402823466e38f;
    #pragma unroll
    for (int j = 0; j < CHUNKS; ++j) {
        float4 k4 = krow[tid + j * BLOCK];
        float d0 = (qv - k4.x) * wv;
        float d1 = (qv - k4.y) * wv;
        float d2 = (qv - k4.z) * wv;
        float d3 = (qv - k4.w) * wv;
        sc[j][0] = -0.5f * d0 * d0;
        sc[j][1] = -0.5f * d1 * d1;
        sc[j][2] = -0.5f * d2 * d2;
        sc[j][3] = -0.5f * d3 * d3;
        lmax = fmaxf(lmax, fmaxf(fmaxf(sc[j][0], sc[j][1]), fmaxf(sc[j][2], sc[j][3])));
    }

    // Block max: wave shfl reduce, then across 4 waves via LDS.
    #pragma unroll
    for (int off = 32; off > 0; off >>= 1)
        lmax = fmaxf(lmax, __shfl_down(lmax, off));

    __shared__ float smax[4];
    __shared__ float ssum[4];
    __shared__ float sdot[4];
    if (lane == 0) smax[wave] = lmax;
    __syncthreads();
    const float m = fmaxf(fmaxf(smax[0], smax[1]), fmaxf(smax[2], smax[3]));

    // Pass 2: exp(score - m), fused with coalesced value loads; accumulate
    // denominator and weighted sum.
    float lsum = 0.0f, ldot = 0.0f;
    #pragma unroll
    for (int j = 0; j < CHUNKS; ++j) {
        float4 v4 = vrow[tid + j * BLOCK];
        float p0 = expf(sc[j][0] - m);
        float p1 = expf(sc[j][1] - m);
        float p2 = expf(sc[j][2] - m);
        float p3 = expf(sc[j][3] - m);
        lsum += (p0 + p1) + (p2 + p3);
        ldot = fmaf(p0, v4.x, ldot);
        ldot = fmaf(p1, v4.y, ldot);
        ldot = fmaf(p2, v4.z, ldot);
        ldot = fmaf(p3, v4.w, ldot);
    }

    #pragma unroll
    for (int off = 32; off > 0; off >>= 1) {
        lsum += __shfl_down(lsum, off);
        ldot += __shfl_down(ldot, off);
    }
    if (lane == 0) { ssum[wave] = lsum; sdot[wave] = ldot; }
    __syncthreads();

    if (tid == 0) {
        float S = (ssum[0] + ssum[1]) + (ssum[2] + ssum[3]);
        float D = (sdot[0] + sdot[1]) + (sdot[2] + sdot[3]);
        out[row] = D / S;
    }
}

extern "C" void kernel_launch(void* const* d_in, const int* in_sizes, int n_in,
                              void* d_out, int out_size, void* d_ws, size_t ws_size,
                              hipStream_t stream) {
    const float* queries = (const float*)d_in[0];
    const float* keys    = (const float*)d_in[1];
    const float* values  = (const float*)d_in[2];
    const float* w       = (const float*)d_in[3];
    float* out = (float*)d_out;

    nw_regression_kernel<<<N_ROWS, BLOCK, 0, stream>>>(queries, keys, values, w, out);
}

// Round 2
// 43.812 us; speedup vs baseline: 1.0020x; 1.0020x over previous
//
#include <hip/hip_runtime.h>
#include <math.h>

// Nadaraya-Watson kernel regression:
//   scores[n,k] = -0.5 * ((q[n] - keys[n,k]) * w)^2
//   out[n]      = sum_k softmax(scores[n,:])[k] * values[n,k]
// N = 8192 rows, K = 4096 cols, float32. Memory-bound: 268 MB/pass,
// ~half L3-resident in steady state (FETCH_SIZE ~134 MB measured R1).
//
// R2 change: preload keys AND values into registers up front (8x float4 in
// flight per thread) so the max-reduction barrier's vmcnt(0) drain doesn't
// serialize the two memory phases. Values live in regs across the barrier.

#define N_ROWS 8192
#define K_DIM  4096
#define BLOCK  256
#define CHUNKS (K_DIM / (BLOCK * 4))   // 4 float4 chunks per thread

__global__ __launch_bounds__(BLOCK) void nw_regression_kernel(
    const float* __restrict__ queries,
    const float* __restrict__ keys,
    const float* __restrict__ values,
    const float* __restrict__ w,
    float* __restrict__ out)
{
    const int row  = blockIdx.x;
    const int tid  = threadIdx.x;
    const int wave = tid >> 6;
    const int lane = tid & 63;

    const float qv = queries[row];
    const float wv = w[0];

    const float4* krow = reinterpret_cast<const float4*>(keys   + (size_t)row * K_DIM);
    const float4* vrow = reinterpret_cast<const float4*>(values + (size_t)row * K_DIM);

    // Issue ALL loads up front: 8 float4 per thread in flight (4 key + 4 val).
    float4 k4[CHUNKS], v4[CHUNKS];
    #pragma unroll
    for (int j = 0; j < CHUNKS; ++j) k4[j] = krow[tid + j * BLOCK];
    #pragma unroll
    for (int j = 0; j < CHUNKS; ++j) v4[j] = vrow[tid + j * BLOCK];

    // Scores in place (overwrite k4 regs), track local max. All scores <= 0.
    float sc[CHUNKS][4];
    float lmax = -3.402823466e38f;
    #pragma unroll
    for (int j = 0; j < CHUNKS; ++j) {
        float d0 = (qv - k4[j].x) * wv;
        float d1 = (qv - k4[j].y) * wv;
        float d2 = (qv - k4[j].z) * wv;
        float d3 = (qv - k4[j].w) * wv;
        sc[j][0] = -0.5f * d0 * d0;
        sc[j][1] = -0.5f * d1 * d1;
        sc[j][2] = -0.5f * d2 * d2;
        sc[j][3] = -0.5f * d3 * d3;
        lmax = fmaxf(lmax, fmaxf(fmaxf(sc[j][0], sc[j][1]), fmaxf(sc[j][2], sc[j][3])));
    }

    // Block max: shfl within wave, LDS across the 4 waves.
    #pragma unroll
    for (int off = 32; off > 0; off >>= 1)
        lmax = fmaxf(lmax, __shfl_down(lmax, off));

    __shared__ float smax[4];
    __shared__ float ssum[4];
    __shared__ float sdot[4];
    if (lane == 0) smax[wave] = lmax;
    __syncthreads();
    const float m = fmaxf(fmaxf(smax[0], smax[1]), fmaxf(smax[2], smax[3]));

    // exp(score - m) fused with the register-resident values.
    const float LOG2E = 1.442695040888963f;
    float lsum = 0.0f, ldot = 0.0f;
    #pragma unroll
    for (int j = 0; j < CHUNKS; ++j) {
        float p0 = __builtin_amdgcn_exp2f((sc[j][0] - m) * LOG2E);
        float p1 = __builtin_amdgcn_exp2f((sc[j][1] - m) * LOG2E);
        float p2 = __builtin_amdgcn_exp2f((sc[j][2] - m) * LOG2E);
        float p3 = __builtin_amdgcn_exp2f((sc[j][3] - m) * LOG2E);
        lsum += (p0 + p1) + (p2 + p3);
        ldot = fmaf(p0, v4[j].x, ldot);
        ldot = fmaf(p1, v4[j].y, ldot);
        ldot = fmaf(p2, v4[j].z, ldot);
        ldot = fmaf(p3, v4[j].w, ldot);
    }

    #pragma unroll
    for (int off = 32; off > 0; off >>= 1) {
        lsum += __shfl_down(lsum, off);
        ldot += __shfl_down(ldot, off);
    }
    if (lane == 0) { ssum[wave] = lsum; sdot[wave] = ldot; }
    __syncthreads();

    if (tid == 0) {
        float S = (ssum[0] + ssum[1]) + (ssum[2] + ssum[3]);
        float D = (sdot[0] + sdot[1]) + (sdot[2] + sdot[3]);
        out[row] = D / S;
    }
}

extern "C" void kernel_launch(void* const* d_in, const int* in_sizes, int n_in,
                              void* d_out, int out_size, void* d_ws, size_t ws_size,
                              hipStream_t stream) {
    const float* queries = (const float*)d_in[0];
    const float* keys    = (const float*)d_in[1];
    const float* values  = (const float*)d_in[2];
    const float* w       = (const float*)d_in[3];
    float* out = (float*)d_out;

    nw_regression_kernel<<<N_ROWS, BLOCK, 0, stream>>>(queries, keys, values, w, out);
}